// Round 7
// baseline (141.601 us; speedup 1.0000x reference)
//
#include <hip/hip_runtime.h>
#include <hip/hip_fp16.h>

// SuppLayer: out[b,c] = exp( sum_s x[b, cm[c,s]] * w[c,s] )
// B=4096, NCLASS=1000, NSUPP=64, NCHUNK=4096.
//
// Structure (best measured: R4): 512 blocks x 1024 thr, BT=8 rows/block,
// 64 KB fp16 LDS tile (slot idx = 16 B = 8 rows at column idx), 2 blocks/CU.
// One class per thread; cm/w pre-transposed to [sg][class] (coalesced).
//
// R7: attack the MEASURED 4.2M LDS bank-conflict cycles. cm is static and
// the dot-product is order-invariant, so the pre-pass counting-sorts each
// class's 64 (idx,w) pairs by rotated quad key ((idx&7)-(c&7))&7. At gather
// position j, lane c then reads quad ~ (j/8 + c)&7 -> consecutive lanes
// spread evenly over the 8 LDS quad-groups -> near-minimal serialization.
// Plus: first cm/w loads hoisted above staging; two-deep cm/w prefetch.

constexpr int B_       = 4096;
constexpr int NCLASS_  = 1000;
constexpr int NSUPP_   = 64;
constexpr int NCHUNK_  = 4096;
constexpr int BT       = 8;      // batch rows per block
constexpr int THREADS_ = 1024;
constexpr int SG_      = NSUPP_ / 4;            // 16 int4/float4 groups
constexpr size_t CMT_BYTES = (size_t)SG_ * NCLASS_ * 16;   // 256 KB
constexpr size_t WS_NEEDED = 2 * CMT_BYTES;                // 512 KB

// ---- pre-pass: per class, counting-sort (idx,w) by rotated quad key and
// write into [sg][class] transposed layout (int4/float4 components). ----
__global__ void build_cw_kernel(const int*   __restrict__ cm,
                                const float* __restrict__ w,
                                int*         __restrict__ cmT,
                                float*       __restrict__ wT)
{
    const int c = blockIdx.x * 256 + threadIdx.x;
    if (c >= NCLASS_) return;
    const int*   ci = cm + c * NSUPP_;
    const float* wi = w  + c * NSUPP_;

    int cnt[8] = {0, 0, 0, 0, 0, 0, 0, 0};
    int idxbuf[NSUPP_];
    #pragma unroll 8
    for (int s = 0; s < NSUPP_; ++s) {
        const int v = ci[s];
        idxbuf[s] = v;
        ++cnt[(v - c) & 7];
    }
    int pos[8];
    pos[0] = 0;
    #pragma unroll
    for (int r = 1; r < 8; ++r) pos[r] = pos[r - 1] + cnt[r - 1];

    #pragma unroll 8
    for (int s = 0; s < NSUPP_; ++s) {
        const int v = idxbuf[s];
        const int r = (v - c) & 7;
        const int j = pos[r]++;
        const int dst = ((j >> 2) * NCLASS_ + c) * 4 + (j & 3);
        cmT[dst] = v;
        wT [dst] = wi[s];
    }
}

template <bool USET>
__global__ __launch_bounds__(THREADS_, 8)
void supp_gather_kernel(const float* __restrict__ x,
                        const float* __restrict__ wSupp,
                        const int*   __restrict__ cmap,
                        const float4* __restrict__ wT,
                        const int4*   __restrict__ cmT,
                        float*       __restrict__ out)
{
    // tile[c*4 + k] = half2(row 2k, row 2k+1) at column c   (64 KB)
    __shared__ __align__(16) __half2 tile[NCHUNK_ * (BT / 2)];

    const int t  = threadIdx.x;
    const int rb = blockIdx.x * BT;   // first batch row of this tile

    // ---- hoist first cm/w loads above staging (hide L2 latency) ----
    int4   ci[2];
    float4 wf[2];
    if (t < NCLASS_) {
        if constexpr (USET) {
            ci[0] = cmT[0 * NCLASS_ + t];  wf[0] = wT[0 * NCLASS_ + t];
            ci[1] = cmT[1 * NCLASS_ + t];  wf[1] = wT[1 * NCLASS_ + t];
        } else {
            ci[0] = reinterpret_cast<const int4*>(cmap + t * NSUPP_)[0];
            wf[0] = reinterpret_cast<const float4*>(wSupp + t * NSUPP_)[0];
            ci[1] = reinterpret_cast<const int4*>(cmap + t * NSUPP_)[1];
            wf[1] = reinterpret_cast<const float4*>(wSupp + t * NSUPP_)[1];
        }
    }

    // ---- stage: 8 rows of x -> fp16, transposed into LDS ----
    // thread t owns columns col = t + 1024p. Global: 4B coalesced.
    // LDS write: float4 at byte addr col*16 -> 16B lane stride, conflict-free.
    #pragma unroll
    for (int p = 0; p < NCHUNK_ / THREADS_; ++p) {   // 4 iterations
        const int col = t + THREADS_ * p;
        float v[BT];
        #pragma unroll
        for (int bi = 0; bi < BT; ++bi)
            v[bi] = x[(size_t)(rb + bi) * NCHUNK_ + col];
        __half2 h[BT / 2];
        #pragma unroll
        for (int k = 0; k < BT / 2; ++k)
            h[k] = __floats2half2_rn(v[2 * k], v[2 * k + 1]);
        *reinterpret_cast<float4*>(&tile[(size_t)col * 4]) =
            *reinterpret_cast<float4*>(h);
    }
    __syncthreads();

    // ---- gather: one class per thread, two-deep cm/w pipeline ----
    if (t < NCLASS_) {
        const int c = t;
        const float4* tile4 = reinterpret_cast<const float4*>(tile);
        float acc[BT] = {0.f, 0.f, 0.f, 0.f, 0.f, 0.f, 0.f, 0.f};

        #pragma unroll
        for (int sg = 0; sg < SG_; ++sg) {
            const int cur = sg & 1;
            const int4   cc = ci[cur];
            const float4 ww = wf[cur];

            // 4 independent ds_read_b128 issued up front
            float4 d0 = tile4[cc.x];
            float4 d1 = tile4[cc.y];
            float4 d2 = tile4[cc.z];
            float4 d3 = tile4[cc.w];

            // prefetch sg+2 (two-deep: covers L2 ~200-300 cyc)
            if (sg + 2 < SG_) {
                if constexpr (USET) {
                    ci[cur] = cmT[(sg + 2) * NCLASS_ + c];
                    wf[cur] = wT [(sg + 2) * NCLASS_ + c];
                } else {
                    ci[cur] = reinterpret_cast<const int4*>(cmap + c * NSUPP_)[sg + 2];
                    wf[cur] = reinterpret_cast<const float4*>(wSupp + c * NSUPP_)[sg + 2];
                }
            }

            const float4* dp[4]  = {&d0, &d1, &d2, &d3};
            const float   ws4[4] = {ww.x, ww.y, ww.z, ww.w};
            #pragma unroll
            for (int j = 0; j < 4; ++j) {
                const __half2* h2 = reinterpret_cast<const __half2*>(dp[j]);
                #pragma unroll
                for (int k = 0; k < 4; ++k) {
                    const float2 f = __half22float2(h2[k]);
                    acc[2 * k]     = fmaf(f.x, ws4[j], acc[2 * k]);
                    acc[2 * k + 1] = fmaf(f.y, ws4[j], acc[2 * k + 1]);
                }
            }
        }
        #pragma unroll
        for (int bi = 0; bi < BT; ++bi)
            out[(size_t)(rb + bi) * NCLASS_ + c] = __expf(acc[bi]);
    }
}

extern "C" void kernel_launch(void* const* d_in, const int* in_sizes, int n_in,
                              void* d_out, int out_size, void* d_ws, size_t ws_size,
                              hipStream_t stream) {
    const float* x  = (const float*)d_in[0];   // (B, NCHUNK) fp32
    const float* w  = (const float*)d_in[1];   // (NCLASS, NSUPP) fp32
    const int*   cm = (const int*)d_in[2];     // (NCLASS, NSUPP) int32
    float*       o  = (float*)d_out;           // (B, NCLASS) fp32

    int*   cmT = (int*)d_ws;
    float* wT  = (float*)((char*)d_ws + CMT_BYTES);

    const dim3 grid(B_ / BT);                  // 512 blocks
    if (ws_size >= WS_NEEDED) {
        build_cw_kernel<<<dim3((NCLASS_ + 255) / 256), dim3(256), 0, stream>>>(
            cm, w, cmT, wT);
        supp_gather_kernel<true><<<grid, dim3(THREADS_), 0, stream>>>(
            x, w, cm, (const float4*)wT, (const int4*)cmT, o);
    } else {
        supp_gather_kernel<false><<<grid, dim3(THREADS_), 0, stream>>>(
            x, w, cm, (const float4*)wT, (const int4*)cmT, o);
    }
}

// Round 8
// 115.685 us; speedup vs baseline: 1.2240x; 1.2240x over previous
//
#include <hip/hip_runtime.h>
#include <hip/hip_fp16.h>

// SuppLayer: out[b,c] = exp( sum_s x[b, cm[c,s]] * w[c,s] )
// B=4096, NCLASS=1000, NSUPP=64, NCHUNK=4096.
//
// Structure = R5 (best measured, ~41us): 512 blocks x 1024 thr, BT=8 rows,
// 64 KB fp16 LDS tile (slot idx = 16 B = 8 rows at column idx), one class
// per thread, cm/w pre-transposed to [sg][class], 4-wide ds_read batching,
// one-deep cm/w prefetch. Gather body is UNCHANGED from R5.
//
// R8 delta (pre-pass only): counting-sort each class's 64 (idx,w) pairs by
// rotated quad key (idx-c)&7. At gather position j, lane c then hits LDS
// bank-quad ~ (c + j/8)&7 -> uniform 8 lanes/quad (b128 minimum) instead of
// random max-load ~13. Sort is spill-free: 1 wave per class, rank via
// __ballot/popcll (registers only). Sum reorder is fp32-safe here.
// (R7 lesson: never combine a data-layout experiment with hot-loop edits.)

constexpr int B_       = 4096;
constexpr int NCLASS_  = 1000;
constexpr int NSUPP_   = 64;
constexpr int NCHUNK_  = 4096;
constexpr int BT       = 8;      // batch rows per block
constexpr int THREADS_ = 1024;
constexpr int SG_      = NSUPP_ / 4;            // 16 int4/float4 groups
constexpr size_t CMT_BYTES = (size_t)SG_ * NCLASS_ * 16;   // 256 KB
constexpr size_t WS_NEEDED = 2 * CMT_BYTES;                // 512 KB

// ---- pre-pass: one wave per class. Sort 64 (idx,w) by key=(idx-c)&7 and
// write to [sg][class] transposed layout. All-register rank computation. ----
__global__ __launch_bounds__(256)
void build_cw_kernel(const int*   __restrict__ cm,
                     const float* __restrict__ w,
                     int*         __restrict__ cmT,
                     float*       __restrict__ wT)
{
    const int t    = threadIdx.x;
    const int c    = blockIdx.x * 4 + (t >> 6);   // 4 classes per block
    const int lane = t & 63;
    if (c >= NCLASS_) return;

    const int   idx = cm[c * NSUPP_ + lane];
    const float wv  = w [c * NSUPP_ + lane];
    const int   key = (idx - c) & 7;

    // stable rank of this element among sorted-by-key order
    const unsigned long long below = ((unsigned long long)1 << lane) - 1;
    int j = 0;
    #pragma unroll
    for (int r = 0; r < 8; ++r) {
        const unsigned long long m = __ballot(key == r);
        const int cnt = __popcll(m);
        if (key > r)  j += cnt;                    // all elems with smaller key
        if (key == r) j += __popcll(m & below);    // stable within key
    }

    const int dst = ((j >> 2) * NCLASS_ + c) * 4 + (j & 3);
    cmT[dst] = idx;
    wT [dst] = wv;
}

template <bool USET>
__global__ __launch_bounds__(THREADS_, 8)
void supp_gather_kernel(const float* __restrict__ x,
                        const float* __restrict__ wSupp,
                        const int*   __restrict__ cmap,
                        const float4* __restrict__ wT,
                        const int4*   __restrict__ cmT,
                        float*       __restrict__ out)
{
    // tile[c*4 + k] = half2(row 2k, row 2k+1) at column c   (64 KB)
    __shared__ __align__(16) __half2 tile[NCHUNK_ * (BT / 2)];

    const int t  = threadIdx.x;
    const int rb = blockIdx.x * BT;   // first batch row of this tile

    // ---- stage: 8 rows of x -> fp16, transposed into LDS ----
    // thread t owns columns col = t + 1024p. Global: 4B coalesced.
    // LDS write: float4 at byte addr col*16 -> 16B lane stride, conflict-free.
    #pragma unroll
    for (int p = 0; p < NCHUNK_ / THREADS_; ++p) {   // 4 iterations
        const int col = t + THREADS_ * p;
        float v[BT];
        #pragma unroll
        for (int bi = 0; bi < BT; ++bi)
            v[bi] = x[(size_t)(rb + bi) * NCHUNK_ + col];
        __half2 h[BT / 2];
        #pragma unroll
        for (int k = 0; k < BT / 2; ++k)
            h[k] = __floats2half2_rn(v[2 * k], v[2 * k + 1]);
        *reinterpret_cast<float4*>(&tile[(size_t)col * 4]) =
            *reinterpret_cast<float4*>(h);
    }
    __syncthreads();

    // ---- gather: one class per thread, software-pipelined (R5 body) ----
    if (t < NCLASS_) {
        const int c = t;
        const float4* tile4 = reinterpret_cast<const float4*>(tile);
        float acc[BT] = {0.f, 0.f, 0.f, 0.f, 0.f, 0.f, 0.f, 0.f};

        int4   ci;
        float4 wf;
        if constexpr (USET) { ci = cmT[c];               wf = wT[c]; }
        else {
            ci = reinterpret_cast<const int4*>(cmap + c * NSUPP_)[0];
            wf = reinterpret_cast<const float4*>(wSupp + c * NSUPP_)[0];
        }

        for (int sg = 0; sg < SG_; ++sg) {
            // issue all 4 independent ds_read_b128 up front
            float4 d0 = tile4[ci.x];
            float4 d1 = tile4[ci.y];
            float4 d2 = tile4[ci.z];
            float4 d3 = tile4[ci.w];
            const float4 wv = wf;

            // prefetch next group's cm/w (L2) past this group's math
            const int sgn = (sg + 1 < SG_) ? sg + 1 : SG_ - 1;
            if constexpr (USET) {
                ci = cmT[sgn * NCLASS_ + c];
                wf = wT [sgn * NCLASS_ + c];
            } else {
                ci = reinterpret_cast<const int4*>(cmap + c * NSUPP_)[sgn];
                wf = reinterpret_cast<const float4*>(wSupp + c * NSUPP_)[sgn];
            }

            const float4* dp[4] = {&d0, &d1, &d2, &d3};
            const float   ws4[4] = {wv.x, wv.y, wv.z, wv.w};
            #pragma unroll
            for (int j = 0; j < 4; ++j) {
                const __half2* h2 = reinterpret_cast<const __half2*>(dp[j]);
                #pragma unroll
                for (int k = 0; k < 4; ++k) {
                    const float2 f = __half22float2(h2[k]);
                    acc[2 * k]     = fmaf(f.x, ws4[j], acc[2 * k]);
                    acc[2 * k + 1] = fmaf(f.y, ws4[j], acc[2 * k + 1]);
                }
            }
        }
        #pragma unroll
        for (int bi = 0; bi < BT; ++bi)
            out[(size_t)(rb + bi) * NCLASS_ + c] = __expf(acc[bi]);
    }
}

extern "C" void kernel_launch(void* const* d_in, const int* in_sizes, int n_in,
                              void* d_out, int out_size, void* d_ws, size_t ws_size,
                              hipStream_t stream) {
    const float* x  = (const float*)d_in[0];   // (B, NCHUNK) fp32
    const float* w  = (const float*)d_in[1];   // (NCLASS, NSUPP) fp32
    const int*   cm = (const int*)d_in[2];     // (NCLASS, NSUPP) int32
    float*       o  = (float*)d_out;           // (B, NCLASS) fp32

    int*   cmT = (int*)d_ws;
    float* wT  = (float*)((char*)d_ws + CMT_BYTES);

    const dim3 grid(B_ / BT);                  // 512 blocks
    if (ws_size >= WS_NEEDED) {
        build_cw_kernel<<<dim3((NCLASS_ + 3) / 4), dim3(256), 0, stream>>>(
            cm, w, cmT, wT);
        supp_gather_kernel<true><<<grid, dim3(THREADS_), 0, stream>>>(
            x, w, cm, (const float4*)wT, (const int4*)cmT, o);
    } else {
        supp_gather_kernel<false><<<grid, dim3(THREADS_), 0, stream>>>(
            x, w, cm, (const float4*)wT, (const int4*)cmT, o);
    }
}

// Round 9
// 115.016 us; speedup vs baseline: 1.2311x; 1.0058x over previous
//
#include <hip/hip_runtime.h>
#include <hip/hip_fp16.h>

// SuppLayer: out[b,c] = exp( sum_s x[b, cm[c,s]] * w[c,s] )
// B=4096, NCLASS=1000, NSUPP=64, NCHUNK=4096.
//
// R9: BT=16 rows per block (256 blocks x 1024 thr, 1 block/CU).
// LDS tile 128 KB fp16, slot idx = 32 B = 16 rows at column idx
// -> one address, two ds_read_b128 (offset 0 / 16) per (class,s).
// Halves cm/w L2 traffic, barrier rounds, per-row addressing vs BT=8.
// One class per thread; cm/w pre-transposed to [sg][class] (coalesced),
// pre-pass also counting-sorts each class's pairs by (idx-c)&3 to balance
// LDS phase groups. First cm/w group prefetched before staging (128-VGPR
// budget now — R7's spill trap was the 64-cap).

constexpr int B_       = 4096;
constexpr int NCLASS_  = 1000;
constexpr int NSUPP_   = 64;
constexpr int NCHUNK_  = 4096;
constexpr int BT       = 16;     // batch rows per block
constexpr int THREADS_ = 1024;
constexpr int SG_      = NSUPP_ / 4;            // 16 int4/float4 groups
constexpr size_t CMT_BYTES = (size_t)SG_ * NCLASS_ * 16;   // 256 KB
constexpr size_t WS_NEEDED = 2 * CMT_BYTES;                // 512 KB

// ---- pre-pass: one wave per class. Sort 64 (idx,w) by key=(idx-c)&3 and
// write to [sg][class] transposed layout. All-register rank computation. ----
__global__ __launch_bounds__(256)
void build_cw_kernel(const int*   __restrict__ cm,
                     const float* __restrict__ w,
                     int*         __restrict__ cmT,
                     float*       __restrict__ wT)
{
    const int t    = threadIdx.x;
    const int c    = blockIdx.x * 4 + (t >> 6);   // 4 classes per block
    const int lane = t & 63;
    if (c >= NCLASS_) return;

    const int   idx = cm[c * NSUPP_ + lane];
    const float wv  = w [c * NSUPP_ + lane];
    const int   key = (idx - c) & 3;

    // stable rank of this element in sorted-by-key order
    const unsigned long long below = ((unsigned long long)1 << lane) - 1;
    int j = 0;
    #pragma unroll
    for (int r = 0; r < 4; ++r) {
        const unsigned long long m = __ballot(key == r);
        if (key > r)  j += __popcll(m);
        if (key == r) j += __popcll(m & below);
    }

    const int dst = ((j >> 2) * NCLASS_ + c) * 4 + (j & 3);
    cmT[dst] = idx;
    wT [dst] = wv;
}

template <bool USET>
__global__ __launch_bounds__(THREADS_, 4)
void supp_gather_kernel(const float* __restrict__ x,
                        const float* __restrict__ wSupp,
                        const int*   __restrict__ cmap,
                        const float4* __restrict__ wT,
                        const int4*   __restrict__ cmT,
                        float*       __restrict__ out)
{
    // tile slot idx (32 B) = half2 pairs of rows (2k,2k+1), k=0..7  (128 KB)
    __shared__ __align__(16) __half2 tile[NCHUNK_ * (BT / 2)];

    const int t  = threadIdx.x;
    const int rb = blockIdx.x * BT;   // first batch row of this tile

    // ---- prefetch first cm/w group before staging (hide L2 latency) ----
    int4   ci;
    float4 wf;
    if (t < NCLASS_) {
        if constexpr (USET) { ci = cmT[t]; wf = wT[t]; }
        else {
            ci = reinterpret_cast<const int4*>(cmap + t * NSUPP_)[0];
            wf = reinterpret_cast<const float4*>(wSupp + t * NSUPP_)[0];
        }
    }

    // ---- stage: 16 rows of x -> fp16, transposed into LDS ----
    // thread t owns columns col = t + 1024p; 4B coalesced global loads.
    // LDS: two b128 writes per col at byte addr col*32 (+16): 2-way quad
    // aliasing between lane pairs = free (m136).
    #pragma unroll
    for (int p = 0; p < NCHUNK_ / THREADS_; ++p) {   // 4 iterations
        const int col = t + THREADS_ * p;
        float v[BT];
        #pragma unroll
        for (int bi = 0; bi < BT; ++bi)
            v[bi] = x[(size_t)(rb + bi) * NCHUNK_ + col];
        __half2 h[BT / 2];
        #pragma unroll
        for (int k = 0; k < BT / 2; ++k)
            h[k] = __floats2half2_rn(v[2 * k], v[2 * k + 1]);
        *reinterpret_cast<float4*>(&tile[(size_t)col * 8]) =
            *reinterpret_cast<float4*>(&h[0]);
        *reinterpret_cast<float4*>(&tile[(size_t)col * 8 + 4]) =
            *reinterpret_cast<float4*>(&h[4]);
    }
    __syncthreads();

    // ---- gather: one class per thread, one-deep cm/w pipeline ----
    if (t < NCLASS_) {
        const int c = t;
        const float4* tile4 = reinterpret_cast<const float4*>(tile);
        float acc[BT];
        #pragma unroll
        for (int bi = 0; bi < BT; ++bi) acc[bi] = 0.f;

        for (int sg = 0; sg < SG_; ++sg) {
            // 8 independent ds_read_b128 (2 per index) issued up front
            float4 d0a = tile4[2 * ci.x],     d0b = tile4[2 * ci.x + 1];
            float4 d1a = tile4[2 * ci.y],     d1b = tile4[2 * ci.y + 1];
            float4 d2a = tile4[2 * ci.z],     d2b = tile4[2 * ci.z + 1];
            float4 d3a = tile4[2 * ci.w],     d3b = tile4[2 * ci.w + 1];
            const float4 wv = wf;

            // prefetch next group's cm/w (L2) past this group's math
            const int sgn = (sg + 1 < SG_) ? sg + 1 : SG_ - 1;
            if constexpr (USET) {
                ci = cmT[sgn * NCLASS_ + c];
                wf = wT [sgn * NCLASS_ + c];
            } else {
                ci = reinterpret_cast<const int4*>(cmap + c * NSUPP_)[sgn];
                wf = reinterpret_cast<const float4*>(wSupp + c * NSUPP_)[sgn];
            }

            const float4* dpa[4] = {&d0a, &d1a, &d2a, &d3a};
            const float4* dpb[4] = {&d0b, &d1b, &d2b, &d3b};
            const float   ws4[4] = {wv.x, wv.y, wv.z, wv.w};
            #pragma unroll
            for (int j = 0; j < 4; ++j) {
                const __half2* ha = reinterpret_cast<const __half2*>(dpa[j]);
                const __half2* hb = reinterpret_cast<const __half2*>(dpb[j]);
                #pragma unroll
                for (int k = 0; k < 4; ++k) {
                    const float2 fa = __half22float2(ha[k]);
                    const float2 fb = __half22float2(hb[k]);
                    acc[2 * k]      = fmaf(fa.x, ws4[j], acc[2 * k]);
                    acc[2 * k + 1]  = fmaf(fa.y, ws4[j], acc[2 * k + 1]);
                    acc[8 + 2 * k]     = fmaf(fb.x, ws4[j], acc[8 + 2 * k]);
                    acc[8 + 2 * k + 1] = fmaf(fb.y, ws4[j], acc[8 + 2 * k + 1]);
                }
            }
        }
        #pragma unroll
        for (int bi = 0; bi < BT; ++bi)
            out[(size_t)(rb + bi) * NCLASS_ + c] = __expf(acc[bi]);
    }
}

extern "C" void kernel_launch(void* const* d_in, const int* in_sizes, int n_in,
                              void* d_out, int out_size, void* d_ws, size_t ws_size,
                              hipStream_t stream) {
    const float* x  = (const float*)d_in[0];   // (B, NCHUNK) fp32
    const float* w  = (const float*)d_in[1];   // (NCLASS, NSUPP) fp32
    const int*   cm = (const int*)d_in[2];     // (NCLASS, NSUPP) int32
    float*       o  = (float*)d_out;           // (B, NCLASS) fp32

    int*   cmT = (int*)d_ws;
    float* wT  = (float*)((char*)d_ws + CMT_BYTES);

    const dim3 grid(B_ / BT);                  // 256 blocks
    if (ws_size >= WS_NEEDED) {
        build_cw_kernel<<<dim3((NCLASS_ + 3) / 4), dim3(256), 0, stream>>>(
            cm, w, cmT, wT);
        supp_gather_kernel<true><<<grid, dim3(THREADS_), 0, stream>>>(
            x, w, cm, (const float4*)wT, (const int4*)cmT, o);
    } else {
        supp_gather_kernel<false><<<grid, dim3(THREADS_), 0, stream>>>(
            x, w, cm, (const float4*)wT, (const int4*)cmT, o);
    }
}